// Round 1
// baseline (102.469 us; speedup 1.0000x reference)
//
#include <hip/hip_runtime.h>

// SmallSMBlock: per-pixel 3x3 kernel prediction (Conv2d(1,9,3,'same') on image)
// then apply the predicted 9-tap kernel at each pixel to 8 batches of x.
// Memory-bound: ideal traffic ~68 MB (image 4 + x 32 + y 32) -> ~11 us floor.
// Strategy: fully fused, 32x32 tiles + 1-px halo staged in LDS, K[9] per pixel
// held in registers, double-buffered x staging (1 sync per batch).

#define H  1024
#define W  1024
#define NB 8
#define TD 32            // tile dim (pixels)
#define TP 34            // tile + halo
#define TT (TP * TP)     // 1156 elements per staged tile

__global__ __launch_bounds__(256)
void smblock_kernel(const float* __restrict__ image,
                    const float* __restrict__ x,
                    const float* __restrict__ kw,   // (9,1,3,3)
                    const float* __restrict__ kb,   // (9,)
                    float* __restrict__ y)          // (8,1,H,W)
{
    __shared__ float simg[TT];
    __shared__ float sx[2][TT];

    const int h0  = blockIdx.y * TD;
    const int w0  = blockIdx.x * TD;
    const int tid = threadIdx.x;

    // ---- stage image tile + batch-0 x tile (zero halo = SAME padding) ----
    #pragma unroll
    for (int k = 0; k < 5; ++k) {
        int idx = tid + k * 256;
        if (idx < TT) {
            int rr = idx / TP, cc = idx - rr * TP;
            int h = h0 + rr - 1, w = w0 + cc - 1;
            bool ok = ((unsigned)h < H) && ((unsigned)w < W);
            size_t g = (size_t)h * W + w;
            simg[idx]  = ok ? image[g] : 0.f;
            sx[0][idx] = ok ? x[g]     : 0.f;
        }
    }
    __syncthreads();

    const int c  = tid & 31;   // pixel col within tile
    const int r0 = tid >> 5;   // base pixel row; handles r0 + 8*p, p=0..3

    // ---- per-pixel predicted kernel K[p][j] = kb[j] + sum_{a,d} kw[j,a,d]*img ----
    float K[4][9];
    #pragma unroll
    for (int p = 0; p < 4; ++p) {
        #pragma unroll
        for (int j = 0; j < 9; ++j) K[p][j] = kb[j];
        int r = r0 + p * 8;
        #pragma unroll
        for (int a = 0; a < 3; ++a) {
            #pragma unroll
            for (int d = 0; d < 3; ++d) {
                float iv = simg[(r + a) * TP + (c + d)];
                #pragma unroll
                for (int j = 0; j < 9; ++j)
                    K[p][j] += kw[j * 9 + a * 3 + d] * iv;  // uniform -> s_load
            }
        }
    }

    // ---- apply per batch; double-buffered x tiles, 1 sync/batch ----
    #pragma unroll
    for (int b = 0; b < NB; ++b) {
        const float* sxb = sx[b & 1];

        // prefetch next batch tile to registers (overlaps compute below)
        float pre[5];
        if (b + 1 < NB) {
            const float* xn = x + (size_t)(b + 1) * (H * W);
            #pragma unroll
            for (int k = 0; k < 5; ++k) {
                int idx = tid + k * 256;
                float v = 0.f;
                if (idx < TT) {
                    int rr = idx / TP, cc = idx - rr * TP;
                    int h = h0 + rr - 1, w = w0 + cc - 1;
                    if (((unsigned)h < H) && ((unsigned)w < W))
                        v = xn[(size_t)h * W + w];
                }
                pre[k] = v;
            }
        }

        // compute y[b] for this thread's 4 pixels
        #pragma unroll
        for (int p = 0; p < 4; ++p) {
            int r = r0 + p * 8;
            float acc = 0.f;
            #pragma unroll
            for (int a = 0; a < 3; ++a)
                #pragma unroll
                for (int d = 0; d < 3; ++d)
                    acc += sxb[(r + a) * TP + (c + d)] * K[p][3 * a + d];
            y[((size_t)b * H + (h0 + r)) * W + (w0 + c)] = acc;
        }

        // commit prefetch into the other buffer
        if (b + 1 < NB) {
            float* dst = sx[(b + 1) & 1];
            #pragma unroll
            for (int k = 0; k < 5; ++k) {
                int idx = tid + k * 256;
                if (idx < TT) dst[idx] = pre[k];
            }
            __syncthreads();
        }
    }
}

extern "C" void kernel_launch(void* const* d_in, const int* in_sizes, int n_in,
                              void* d_out, int out_size, void* d_ws, size_t ws_size,
                              hipStream_t stream)
{
    const float* image = (const float*)d_in[0];  // (1,1024,1024)
    const float* x     = (const float*)d_in[1];  // (8,1,1024,1024)
    const float* kw    = (const float*)d_in[2];  // (9,1,3,3)
    const float* kb    = (const float*)d_in[3];  // (9,)
    float* y = (float*)d_out;                    // (8,1,1024,1024)

    dim3 grid(W / TD, H / TD);
    smblock_kernel<<<grid, 256, 0, stream>>>(image, x, kw, kb, y);
}

// Round 2
// 100.926 us; speedup vs baseline: 1.0153x; 1.0153x over previous
//
#include <hip/hip_runtime.h>

// SmallSMBlock: K = Conv2d(1,9,3,'same')(image)+b per pixel; y[b] = 9-tap apply to x[b].
// Memory-bound: ideal ~68 MB traffic -> ~11-12 us floor at 6.3 TB/s.
// R2: vectorized staging (dwordx4 interior + 132 halo lanes), LDS stride 36 so
// apply reads are ds_read_b128+b64, float4 stores. 1 row x 4 adjacent cols/thread.

#define H  1024
#define W  1024
#define NB 8
#define TD 32            // tile dim (pixels)
#define TP 34            // padded tile dim
#define LS 36            // LDS row stride (floats): keeps 4*cg reads 16B-aligned
#define LT (TP * LS)     // floats per staged tile (34*36 = 1224)

__global__ __launch_bounds__(256)
void smblock_kernel(const float* __restrict__ image,
                    const float* __restrict__ x,
                    const float* __restrict__ kw,   // (9,1,3,3)
                    const float* __restrict__ kb,   // (9,)
                    float* __restrict__ y)          // (8,1,H,W)
{
    __shared__ float simg[LT];
    __shared__ float sx[2][LT];

    const int h0  = blockIdx.y * TD;
    const int w0  = blockIdx.x * TD;
    const int tid = threadIdx.x;
    const int r   = tid >> 3;      // pixel row 0..31
    const int cg  = tid & 7;       // col group: pixel cols 4cg..4cg+3

    // interior global offset (16B aligned: w0+4cg is a multiple of 4)
    const size_t gint = (size_t)(h0 + r) * W + (w0 + 4 * cg);
    const int    lint = (r + 1) * LS + (4 * cg + 1);   // LDS dest (padded coords)

    // ---- halo assignment: 132 border elements of the 34x34 padded tile ----
    // wave0 lanes 0..33: top row; wave1: bottom row; wave2 lanes 0..31: left col;
    // wave3 lanes 0..31: right col.
    int hr = -1, hc = -1;
    {
        const int wv = tid >> 6, ln = tid & 63;
        if      (wv == 0) { if (ln < TP) { hr = 0;      hc = ln;     } }
        else if (wv == 1) { if (ln < TP) { hr = TP - 1; hc = ln;     } }
        else if (wv == 2) { if (ln < TD) { hr = ln + 1; hc = 0;      } }
        else              { if (ln < TD) { hr = ln + 1; hc = TP - 1; } }
    }
    const bool has_halo = (hr >= 0);
    const int  gh = h0 + hr - 1, gw = w0 + hc - 1;
    const bool hin = has_halo && ((unsigned)gh < H) && ((unsigned)gw < W);
    const size_t ghalo = (size_t)gh * W + gw;
    const int    lhalo = hr * LS + hc;

    // ---- stage image + batch-0 x ----
    {
        float4 iv = *(const float4*)(image + gint);
        float4 xv = *(const float4*)(x + gint);
        float ihv = hin ? image[ghalo] : 0.f;
        float xhv = hin ? x[ghalo]     : 0.f;
        simg[lint]  = iv.x; simg[lint+1]  = iv.y; simg[lint+2]  = iv.z; simg[lint+3]  = iv.w;
        sx[0][lint] = xv.x; sx[0][lint+1] = xv.y; sx[0][lint+2] = xv.z; sx[0][lint+3] = xv.w;
        if (has_halo) { simg[lhalo] = ihv; sx[0][lhalo] = xhv; }
    }
    __syncthreads();

    // ---- per-pixel predicted kernels: K[j][t] for pixels (r, 4cg+j), taps t ----
    float K[4][9];
    #pragma unroll
    for (int j = 0; j < 4; ++j)
        #pragma unroll
        for (int t = 0; t < 9; ++t) K[j][t] = kb[t];

    #pragma unroll
    for (int a = 0; a < 3; ++a) {
        const float* row = &simg[(r + a) * LS + 4 * cg];
        float4 f4 = *(const float4*)row;        // 16B-aligned (LS=36)
        float2 f2 = *(const float2*)(row + 4);
        float wv[6] = { f4.x, f4.y, f4.z, f4.w, f2.x, f2.y };
        #pragma unroll
        for (int d = 0; d < 3; ++d)
            #pragma unroll
            for (int t = 0; t < 9; ++t) {
                float wgt = kw[t * 9 + 3 * a + d];   // wave-uniform -> s_load
                #pragma unroll
                for (int j = 0; j < 4; ++j)
                    K[j][t] += wgt * wv[j + d];
            }
    }

    // ---- apply per batch; double-buffered x, one sync per batch ----
    #pragma unroll
    for (int b = 0; b < NB; ++b) {
        // prefetch next batch tile into registers (overlaps compute)
        float4 pv; float phv = 0.f;
        if (b + 1 < NB) {
            const float* xn = x + (size_t)(b + 1) * ((size_t)H * W);
            pv  = *(const float4*)(xn + gint);
            if (hin) phv = xn[ghalo];
        }

        const float* sb = sx[b & 1];
        float a0 = 0.f, a1 = 0.f, a2 = 0.f, a3 = 0.f;
        #pragma unroll
        for (int a = 0; a < 3; ++a) {
            const float* row = &sb[(r + a) * LS + 4 * cg];
            float4 f4 = *(const float4*)row;    // ds_read_b128
            float2 f2 = *(const float2*)(row + 4);
            float wv[6] = { f4.x, f4.y, f4.z, f4.w, f2.x, f2.y };
            #pragma unroll
            for (int d = 0; d < 3; ++d) {
                a0 += wv[0 + d] * K[0][3 * a + d];
                a1 += wv[1 + d] * K[1][3 * a + d];
                a2 += wv[2 + d] * K[2][3 * a + d];
                a3 += wv[3 + d] * K[3][3 * a + d];
            }
        }
        float4 o; o.x = a0; o.y = a1; o.z = a2; o.w = a3;
        *(float4*)(y + (size_t)b * ((size_t)H * W) + gint) = o;   // dwordx4 store

        if (b + 1 < NB) {
            float* dst = sx[(b + 1) & 1];
            dst[lint]   = pv.x; dst[lint+1] = pv.y;
            dst[lint+2] = pv.z; dst[lint+3] = pv.w;
            if (has_halo) dst[lhalo] = phv;
            __syncthreads();
        }
    }
}

extern "C" void kernel_launch(void* const* d_in, const int* in_sizes, int n_in,
                              void* d_out, int out_size, void* d_ws, size_t ws_size,
                              hipStream_t stream)
{
    const float* image = (const float*)d_in[0];  // (1,1024,1024)
    const float* x     = (const float*)d_in[1];  // (8,1,1024,1024)
    const float* kw    = (const float*)d_in[2];  // (9,1,3,3)
    const float* kb    = (const float*)d_in[3];  // (9,)
    float* y = (float*)d_out;                    // (8,1,1024,1024)

    dim3 grid(W / TD, H / TD);
    smblock_kernel<<<grid, 256, 0, stream>>>(image, x, kw, kb, y);
}